// Round 23
// baseline (25.660 us; speedup 1.0000x reference)
//
#include <hip/hip_runtime.h>

// SphericalVectorPool on MI355X — MFMA + b128 DS traffic (K-permuted layout).
// Per anchor: D[16 k][4 comp] = sum_src E[k][src] * w[src][comp], one
// v_mfma_f32_16x16x32_f16 per 32-source chunk. 4 sources per lane:
// all LDS writes are b64 (two h2), all fragment reads are b128 via a
// K-permuted row layout (slice order [4g..4g+3, 16+4g..16+4g+3] per chunk —
// legal because MFMA K-permutation cancels when applied to BOTH A and B,
// which R22 validated empirically). E via mu_j=4/j sqrt-chain in packed f16
// (8 exp heads/source + 8 pk_mul/pair). D-map m89-verified: col=lane&15=comp,
// row=4*(lane>>4)+reg=k -> direct dwordx4 store, no shuffle reduce.

constexpr int NR    = 16;
constexpr int BATCH = 2;
constexpr int NSRC  = 2048;
constexpr int MOUT  = 2048;

typedef __fp16 h2 __attribute__((ext_vector_type(2)));
typedef _Float16 f16x8 __attribute__((ext_vector_type(8)));
typedef float f32x4 __attribute__((ext_vector_type(4)));

__global__ __launch_bounds__(64, 1) void svp_kernel(
    const float* __restrict__ f,       // [B,N]
    const float* __restrict__ coords,  // [B,N,3]
    const float* __restrict__ outc,    // [B,M,3]
    const float* __restrict__ mu,      // [16]
    const float* __restrict__ rn,      // [16]
    const float* __restrict__ an0,     // [1]
    const float* __restrict__ an1,     // [1]
    float* __restrict__ out)           // [B,M,64]
{
    const int lane = threadIdx.x;             // one wave per block
    const int anchor = blockIdx.x;            // 0..4095
    const int b = anchor >> 11;
    const int col = lane & 15;
    const int grp = lane >> 4;

    // rows: 8 chunks x 32 halfwords, slice-ordered within chunk; +8 pad
    __shared__ unsigned short eT[16][264];
    __shared__ unsigned short wT[4][264];

    const float NL2E = -1.44269504088896340736f;

    // hoisted: nmu[s] = -log2e * mu[j=16-s]
    float nmu[8];
#pragma unroll
    for (int s = 0; s < 8; ++s) nmu[s] = mu[15 - s] * NL2E;

    const float Rx = outc[(size_t)anchor * 3 + 0];
    const float Ry = outc[(size_t)anchor * 3 + 1];
    const float Rz = outc[(size_t)anchor * 3 + 2];

    f32x4 acc = {0.f, 0.f, 0.f, 0.f};

    const float* cb = coords + (size_t)b * NSRC * 3;
    const float* fb = f + (size_t)b * NSRC;

    // write position: lane's 4 sources land as one contiguous 4-group.
    // chunk = lane>>3 ; t = lane&7 ; pos4 = 8*(t&3) + 4*(t>>2)
    const int whw = 32 * (lane >> 3) + 8 * (lane & 3) + 4 * ((lane >> 2) & 1);

    // read slice (chunk c): halfwords [32c + 8*grp .. +7]
    const int rhw = 8 * grp;

    for (int i = 0; i < NSRC / 256; ++i) {    // 8 iterations, 256 src each
        const int s0 = i * 256 + 4 * lane;    // lane handles s0..s0+3
        const float4 c0 = *(const float4*)(cb + (size_t)s0 * 3);      // x0 y0 z0 x1
        const float4 c1 = *(const float4*)(cb + (size_t)s0 * 3 + 4);  // y1 z1 x2 y2
        const float4 c2 = *(const float4*)(cb + (size_t)s0 * 3 + 8);  // z2 x3 y3 z3
        const float4 f4 = *(const float4*)(fb + s0);

        const float dx0 = c0.x - Rx, dy0 = c0.y - Ry, dz0 = c0.z - Rz;
        const float dx1 = c0.w - Rx, dy1 = c1.x - Ry, dz1 = c1.y - Rz;
        const float dx2 = c1.z - Rx, dy2 = c1.w - Ry, dz2 = c2.x - Rz;
        const float dx3 = c2.y - Rx, dy3 = c2.z - Ry, dz3 = c2.w - Rz;

        const float sq0 = dx0 * dx0 + dy0 * dy0 + dz0 * dz0;
        const float sq1 = dx1 * dx1 + dy1 * dy1 + dz1 * dz1;
        const float sq2 = dx2 * dx2 + dy2 * dy2 + dz2 * dz2;
        const float sq3 = dx3 * dx3 + dy3 * dy3 + dz3 * dz3;
        const float ri0 = __builtin_amdgcn_rsqf(sq0);
        const float ri1 = __builtin_amdgcn_rsqf(sq1);
        const float ri2 = __builtin_amdgcn_rsqf(sq2);
        const float ri3 = __builtin_amdgcn_rsqf(sq3);
        const float d0 = sq0 * ri0, d1 = sq1 * ri1;
        const float d2 = sq2 * ri2, d3 = sq3 * ri3;
        const float t0 = f4.x * ri0, t1 = f4.y * ri1;
        const float t2 = f4.z * ri2, t3 = f4.w * ri3;

        // sqrt-chain in packed f16, two pairs: (s0,s0+1) and (s0+2,s0+3)
        h2 ep0[16], ep1[16];
#pragma unroll
        for (int s = 0; s < 8; ++s) {
            ep0[s] = __builtin_amdgcn_cvt_pkrtz(
                __builtin_amdgcn_exp2f(d0 * nmu[s]),
                __builtin_amdgcn_exp2f(d1 * nmu[s]));
            ep1[s] = __builtin_amdgcn_cvt_pkrtz(
                __builtin_amdgcn_exp2f(d2 * nmu[s]),
                __builtin_amdgcn_exp2f(d3 * nmu[s]));
        }
        ep0[8]  = ep0[0] * ep0[0];    ep1[8]  = ep1[0] * ep1[0];    // E8
        ep0[9]  = ep0[2] * ep0[2];    ep1[9]  = ep1[2] * ep1[2];    // E7
        ep0[10] = ep0[4] * ep0[4];    ep1[10] = ep1[4] * ep1[4];    // E6
        ep0[11] = ep0[6] * ep0[6];    ep1[11] = ep1[6] * ep1[6];    // E5
        ep0[12] = ep0[8] * ep0[8];    ep1[12] = ep1[8] * ep1[8];    // E4
        ep0[13] = ep0[10] * ep0[10];  ep1[13] = ep1[10] * ep1[10];  // E3
        ep0[14] = ep0[12] * ep0[12];  ep1[14] = ep1[12] * ep1[12];  // E2
        ep0[15] = ep0[14] * ep0[14];  ep1[15] = ep1[14] * ep1[14];  // E1

        // LDS scatter: one b64 per row (4 sources), rows k = 15-s
#pragma unroll
        for (int s = 0; s < 16; ++s) {
            uint2 val;
            val.x = __builtin_bit_cast(unsigned, ep0[s]);
            val.y = __builtin_bit_cast(unsigned, ep1[s]);
            *(uint2*)&eT[15 - s][whw] = val;
        }
        {
            uint2 v0, v1, v2, v3;
            v0.x = __builtin_bit_cast(unsigned, __builtin_amdgcn_cvt_pkrtz(f4.x, f4.y));
            v0.y = __builtin_bit_cast(unsigned, __builtin_amdgcn_cvt_pkrtz(f4.z, f4.w));
            v1.x = __builtin_bit_cast(unsigned, __builtin_amdgcn_cvt_pkrtz(t0 * dx0, t1 * dx1));
            v1.y = __builtin_bit_cast(unsigned, __builtin_amdgcn_cvt_pkrtz(t2 * dx2, t3 * dx3));
            v2.x = __builtin_bit_cast(unsigned, __builtin_amdgcn_cvt_pkrtz(t0 * dy0, t1 * dy1));
            v2.y = __builtin_bit_cast(unsigned, __builtin_amdgcn_cvt_pkrtz(t2 * dy2, t3 * dy3));
            v3.x = __builtin_bit_cast(unsigned, __builtin_amdgcn_cvt_pkrtz(t0 * dz0, t1 * dz1));
            v3.y = __builtin_bit_cast(unsigned, __builtin_amdgcn_cvt_pkrtz(t2 * dz2, t3 * dz3));
            *(uint2*)&wT[0][whw] = v0;
            *(uint2*)&wT[1][whw] = v1;
            *(uint2*)&wT[2][whw] = v2;
            *(uint2*)&wT[3][whw] = v3;
        }
        // single-wave block: DS pipeline is in-order per wave; compiler
        // inserts lgkmcnt before dependent reads (validated in R22).

        // 8 MFMA chunks of 32 sources, b128 fragment reads
#pragma unroll
        for (int c = 0; c < 8; ++c) {
            const f16x8 av = *(const f16x8*)&eT[col][32 * c + rhw];
            const f16x8 bv = *(const f16x8*)&wT[col & 3][32 * c + rhw];
            acc = __builtin_amdgcn_mfma_f32_16x16x32_f16(av, bv, acc, 0, 0, 0);
        }
    }

    // D[row=4*grp+r][col]: col = component, row = k (m89-verified map)
    if (col < 4) {
        const float4 r4 = *(const float4*)&rn[4 * grp];
        const float an = (col == 0) ? an0[0] : an1[0];
        float4 o;
        o.x = acc[0] * r4.x * an;
        o.y = acc[1] * r4.y * an;
        o.z = acc[2] * r4.z * an;
        o.w = acc[3] * r4.w * an;
        *(float4*)&out[(size_t)anchor * 64 + col * 16 + 4 * grp] = o;
    }
}

extern "C" void kernel_launch(void* const* d_in, const int* in_sizes, int n_in,
                              void* d_out, int out_size, void* d_ws, size_t ws_size,
                              hipStream_t stream) {
    const float* f      = (const float*)d_in[0];
    const float* coords = (const float*)d_in[1];
    const float* outc   = (const float*)d_in[2];
    const float* mu     = (const float*)d_in[3];
    const float* rn     = (const float*)d_in[4];
    const float* an0    = (const float*)d_in[5];
    const float* an1    = (const float*)d_in[6];
    float* out = (float*)d_out;

    const int anchors = BATCH * MOUT;              // 4096 waves, 1 per block
    svp_kernel<<<anchors, 64, 0, stream>>>(f, coords, outc, mu, rn, an0, an1, out);
}

// Round 24
// 24.786 us; speedup vs baseline: 1.0353x; 1.0353x over previous
//
#include <hip/hip_runtime.h>

// SphericalVectorPool on MI355X — trans-pipe rebalance: 4 exp heads/source.
// R23 post-mortem: wall == trans-pipe occupancy (1024 exp/SIMD x ~15cyc =
// 25.6us, measured 25.5). Fix: heads {16,14,12,10} stay on trans; evens
// {8..1} by packed-f16 squares (as before); odds {15,13,11,9} move to the
// half-idle VALU via E_j = E_{j+1} * exp(-(mu_j - mu_{j+1})*d), correction
// exp(-x) (x = dmu*d <= 0.36) as cubic Taylor in packed f16 (rel err <=8e-4
// worst-case, f16 rounding dominates). MFMA contraction + K-permuted b128
// LDS + direct D-layout store unchanged from R23 (passed, absmax 0.09375).

constexpr int NR    = 16;
constexpr int BATCH = 2;
constexpr int NSRC  = 2048;
constexpr int MOUT  = 2048;

typedef __fp16 h2 __attribute__((ext_vector_type(2)));
typedef _Float16 f16x8 __attribute__((ext_vector_type(8)));
typedef float f32x4 __attribute__((ext_vector_type(4)));

__global__ __launch_bounds__(64, 1) void svp_kernel(
    const float* __restrict__ f,       // [B,N]
    const float* __restrict__ coords,  // [B,N,3]
    const float* __restrict__ outc,    // [B,M,3]
    const float* __restrict__ mu,      // [16]
    const float* __restrict__ rn,      // [16]
    const float* __restrict__ an0,     // [1]
    const float* __restrict__ an1,     // [1]
    float* __restrict__ out)           // [B,M,64]
{
    const int lane = threadIdx.x;             // one wave per block
    const int anchor = blockIdx.x;            // 0..4095
    const int b = anchor >> 11;
    const int col = lane & 15;
    const int grp = lane >> 4;

    __shared__ unsigned short eT[16][264];
    __shared__ unsigned short wT[4][264];

    const float NL2E = -1.44269504088896340736f;

    // exp2 args for the 4 heads: j = 16,14,12,10 -> mu idx 15,13,11,9
    const float nm16 = mu[15] * NL2E;
    const float nm14 = mu[13] * NL2E;
    const float nm12 = mu[11] * NL2E;
    const float nm10 = mu[9]  * NL2E;

    // odd-correction deltas: E_j = E_{j+1} * exp(-(mu_j - mu_{j+1}) d)
    const float dl15 = mu[14] - mu[15];
    const float dl13 = mu[12] - mu[13];
    const float dl11 = mu[10] - mu[11];
    const float dl9  = mu[8]  - mu[9];
    const h2 hD15 = __builtin_amdgcn_cvt_pkrtz(dl15, dl15);
    const h2 hD13 = __builtin_amdgcn_cvt_pkrtz(dl13, dl13);
    const h2 hD11 = __builtin_amdgcn_cvt_pkrtz(dl11, dl11);
    const h2 hD9  = __builtin_amdgcn_cvt_pkrtz(dl9,  dl9);

    // cubic Taylor of exp(-x): ((−x/6 + 1/2)x − 1)x + 1
    const h2 C3 = {(__fp16)(-1.0f / 6.0f), (__fp16)(-1.0f / 6.0f)};
    const h2 C2 = {(__fp16)0.5f,  (__fp16)0.5f};
    const h2 C1 = {(__fp16)-1.0f, (__fp16)-1.0f};
    const h2 C0 = {(__fp16)1.0f,  (__fp16)1.0f};

    const float Rx = outc[(size_t)anchor * 3 + 0];
    const float Ry = outc[(size_t)anchor * 3 + 1];
    const float Rz = outc[(size_t)anchor * 3 + 2];

    f32x4 acc = {0.f, 0.f, 0.f, 0.f};

    const float* cb = coords + (size_t)b * NSRC * 3;
    const float* fb = f + (size_t)b * NSRC;

    const int whw = 32 * (lane >> 3) + 8 * (lane & 3) + 4 * ((lane >> 2) & 1);
    const int rhw = 8 * grp;

    for (int i = 0; i < NSRC / 256; ++i) {    // 8 iterations, 256 src each
        const int s0 = i * 256 + 4 * lane;    // lane handles s0..s0+3
        const float4 c0 = *(const float4*)(cb + (size_t)s0 * 3);      // x0 y0 z0 x1
        const float4 c1 = *(const float4*)(cb + (size_t)s0 * 3 + 4);  // y1 z1 x2 y2
        const float4 c2 = *(const float4*)(cb + (size_t)s0 * 3 + 8);  // z2 x3 y3 z3
        const float4 f4 = *(const float4*)(fb + s0);

        const float dx0 = c0.x - Rx, dy0 = c0.y - Ry, dz0 = c0.z - Rz;
        const float dx1 = c0.w - Rx, dy1 = c1.x - Ry, dz1 = c1.y - Rz;
        const float dx2 = c1.z - Rx, dy2 = c1.w - Ry, dz2 = c2.x - Rz;
        const float dx3 = c2.y - Rx, dy3 = c2.z - Ry, dz3 = c2.w - Rz;

        const float sq0 = dx0 * dx0 + dy0 * dy0 + dz0 * dz0;
        const float sq1 = dx1 * dx1 + dy1 * dy1 + dz1 * dz1;
        const float sq2 = dx2 * dx2 + dy2 * dy2 + dz2 * dz2;
        const float sq3 = dx3 * dx3 + dy3 * dy3 + dz3 * dz3;
        const float ri0 = __builtin_amdgcn_rsqf(sq0);
        const float ri1 = __builtin_amdgcn_rsqf(sq1);
        const float ri2 = __builtin_amdgcn_rsqf(sq2);
        const float ri3 = __builtin_amdgcn_rsqf(sq3);
        const float d0 = sq0 * ri0, d1 = sq1 * ri1;
        const float d2 = sq2 * ri2, d3 = sq3 * ri3;
        const float t0 = f4.x * ri0, t1 = f4.y * ri1;
        const float t2 = f4.z * ri2, t3 = f4.w * ri3;

        // packed distances for the odd-correction path
        const h2 dpk0 = __builtin_amdgcn_cvt_pkrtz(d0, d1);
        const h2 dpk1 = __builtin_amdgcn_cvt_pkrtz(d2, d3);

        // E values indexed by k = j-1, packed per source-pair
        h2 ep0[16], ep1[16];

        // 4 trans heads per source (16 exps / 4 sources)
        ep0[15] = __builtin_amdgcn_cvt_pkrtz(
            __builtin_amdgcn_exp2f(d0 * nm16), __builtin_amdgcn_exp2f(d1 * nm16));
        ep1[15] = __builtin_amdgcn_cvt_pkrtz(
            __builtin_amdgcn_exp2f(d2 * nm16), __builtin_amdgcn_exp2f(d3 * nm16));
        ep0[13] = __builtin_amdgcn_cvt_pkrtz(
            __builtin_amdgcn_exp2f(d0 * nm14), __builtin_amdgcn_exp2f(d1 * nm14));
        ep1[13] = __builtin_amdgcn_cvt_pkrtz(
            __builtin_amdgcn_exp2f(d2 * nm14), __builtin_amdgcn_exp2f(d3 * nm14));
        ep0[11] = __builtin_amdgcn_cvt_pkrtz(
            __builtin_amdgcn_exp2f(d0 * nm12), __builtin_amdgcn_exp2f(d1 * nm12));
        ep1[11] = __builtin_amdgcn_cvt_pkrtz(
            __builtin_amdgcn_exp2f(d2 * nm12), __builtin_amdgcn_exp2f(d3 * nm12));
        ep0[9]  = __builtin_amdgcn_cvt_pkrtz(
            __builtin_amdgcn_exp2f(d0 * nm10), __builtin_amdgcn_exp2f(d1 * nm10));
        ep1[9]  = __builtin_amdgcn_cvt_pkrtz(
            __builtin_amdgcn_exp2f(d2 * nm10), __builtin_amdgcn_exp2f(d3 * nm10));

        // evens via pk squares: 8=16^2, 7=14^2, 6=12^2, 5=10^2, 4=8^2, 3=6^2, 2=4^2, 1=2^2
        ep0[7] = ep0[15] * ep0[15];   ep1[7] = ep1[15] * ep1[15];
        ep0[6] = ep0[13] * ep0[13];   ep1[6] = ep1[13] * ep1[13];
        ep0[5] = ep0[11] * ep0[11];   ep1[5] = ep1[11] * ep1[11];
        ep0[4] = ep0[9]  * ep0[9];    ep1[4] = ep1[9]  * ep1[9];
        ep0[3] = ep0[7]  * ep0[7];    ep1[3] = ep1[7]  * ep1[7];
        ep0[2] = ep0[5]  * ep0[5];    ep1[2] = ep1[5]  * ep1[5];
        ep0[1] = ep0[3]  * ep0[3];    ep1[1] = ep1[3]  * ep1[3];
        ep0[0] = ep0[1]  * ep0[1];    ep1[0] = ep1[1]  * ep1[1];

        // odds via neighbor * cubic-poly correction (VALU pk ops)
#define ODD(K_ODD, K_EVEN, HD)                                            \
        {                                                                 \
            h2 x0 = dpk0 * (HD);                                          \
            h2 x1 = dpk1 * (HD);                                          \
            h2 p0 = C0 + x0 * (C1 + x0 * (C2 + x0 * C3));                 \
            h2 p1 = C0 + x1 * (C1 + x1 * (C2 + x1 * C3));                 \
            ep0[K_ODD] = ep0[K_EVEN] * p0;                                \
            ep1[K_ODD] = ep1[K_EVEN] * p1;                                \
        }
        ODD(14, 15, hD15)   // E15 = E16 * corr
        ODD(12, 13, hD13)   // E13 = E14 * corr
        ODD(10, 11, hD11)   // E11 = E12 * corr
        ODD(8,  9,  hD9)    // E9  = E10 * corr
#undef ODD

        // LDS scatter: one b64 per row k (4 sources)
#pragma unroll
        for (int k = 0; k < 16; ++k) {
            uint2 val;
            val.x = __builtin_bit_cast(unsigned, ep0[k]);
            val.y = __builtin_bit_cast(unsigned, ep1[k]);
            *(uint2*)&eT[k][whw] = val;
        }
        {
            uint2 v0, v1, v2, v3;
            v0.x = __builtin_bit_cast(unsigned, __builtin_amdgcn_cvt_pkrtz(f4.x, f4.y));
            v0.y = __builtin_bit_cast(unsigned, __builtin_amdgcn_cvt_pkrtz(f4.z, f4.w));
            v1.x = __builtin_bit_cast(unsigned, __builtin_amdgcn_cvt_pkrtz(t0 * dx0, t1 * dx1));
            v1.y = __builtin_bit_cast(unsigned, __builtin_amdgcn_cvt_pkrtz(t2 * dx2, t3 * dx3));
            v2.x = __builtin_bit_cast(unsigned, __builtin_amdgcn_cvt_pkrtz(t0 * dy0, t1 * dy1));
            v2.y = __builtin_bit_cast(unsigned, __builtin_amdgcn_cvt_pkrtz(t2 * dy2, t3 * dy3));
            v3.x = __builtin_bit_cast(unsigned, __builtin_amdgcn_cvt_pkrtz(t0 * dz0, t1 * dz1));
            v3.y = __builtin_bit_cast(unsigned, __builtin_amdgcn_cvt_pkrtz(t2 * dz2, t3 * dz3));
            *(uint2*)&wT[0][whw] = v0;
            *(uint2*)&wT[1][whw] = v1;
            *(uint2*)&wT[2][whw] = v2;
            *(uint2*)&wT[3][whw] = v3;
        }

        // 8 MFMA chunks of 32 sources, b128 fragment reads
#pragma unroll
        for (int c = 0; c < 8; ++c) {
            const f16x8 av = *(const f16x8*)&eT[col][32 * c + rhw];
            const f16x8 bv = *(const f16x8*)&wT[col & 3][32 * c + rhw];
            acc = __builtin_amdgcn_mfma_f32_16x16x32_f16(av, bv, acc, 0, 0, 0);
        }
    }

    // D[row=4*grp+r][col]: col = component, row = k (m89-verified map)
    if (col < 4) {
        const float4 r4 = *(const float4*)&rn[4 * grp];
        const float an = (col == 0) ? an0[0] : an1[0];
        float4 o;
        o.x = acc[0] * r4.x * an;
        o.y = acc[1] * r4.y * an;
        o.z = acc[2] * r4.z * an;
        o.w = acc[3] * r4.w * an;
        *(float4*)&out[(size_t)anchor * 64 + col * 16 + 4 * grp] = o;
    }
}

extern "C" void kernel_launch(void* const* d_in, const int* in_sizes, int n_in,
                              void* d_out, int out_size, void* d_ws, size_t ws_size,
                              hipStream_t stream) {
    const float* f      = (const float*)d_in[0];
    const float* coords = (const float*)d_in[1];
    const float* outc   = (const float*)d_in[2];
    const float* mu     = (const float*)d_in[3];
    const float* rn     = (const float*)d_in[4];
    const float* an0    = (const float*)d_in[5];
    const float* an1    = (const float*)d_in[6];
    float* out = (float*)d_out;

    const int anchors = BATCH * MOUT;              // 4096 waves, 1 per block
    svp_kernel<<<anchors, 64, 0, stream>>>(f, coords, outc, mu, rn, an0, an1, out);
}

// Round 25
// 23.648 us; speedup vs baseline: 1.0851x; 1.0481x over previous
//
#include <hip/hip_runtime.h>

// SphericalVectorPool on MI355X — 2 waves/anchor residency test (MFMA regime).
// R24 post-mortem: no pipe-throughput model reaches the measured wall; the
// kernel is latency-chain-bound (load->rsq->exp->squares->DS->MFMA ~900cyc/
// iter) at only 4 waves/SIMD. This round: 128-thr blocks, wave w handles
// sources w*1024..+1023 (8 iters x 128 src, R22 LDS geometry 5.44KB/wave,
// 10.88KB/block -> 15 blocks/CU = 30 waves/CU = 7.5/SIMD, 1.9x residency),
// same total instruction count. E-gen identical to R24 (4 exp heads
// {16,14,12,10}, evens by packed-f16 squares, odds by cubic correction).
// Epilogue: wave1 acc -> LDS, barrier, wave0 combines + scales + stores.

constexpr int NR    = 16;
constexpr int BATCH = 2;
constexpr int NSRC  = 2048;
constexpr int MOUT  = 2048;

typedef __fp16 h2 __attribute__((ext_vector_type(2)));
typedef _Float16 f16x8 __attribute__((ext_vector_type(8)));
typedef float f32x4 __attribute__((ext_vector_type(4)));

__global__ __launch_bounds__(128, 1) void svp_kernel(
    const float* __restrict__ f,       // [B,N]
    const float* __restrict__ coords,  // [B,N,3]
    const float* __restrict__ outc,    // [B,M,3]
    const float* __restrict__ mu,      // [16]
    const float* __restrict__ rn,      // [16]
    const float* __restrict__ an0,     // [1]
    const float* __restrict__ an1,     // [1]
    float* __restrict__ out)           // [B,M,64]
{
    const int tid  = threadIdx.x;
    const int lane = tid & 63;
    const int w    = tid >> 6;                // wave in block: 0..1
    const int anchor = blockIdx.x;            // 0..4095
    const int b = anchor >> 11;
    const int col = lane & 15;
    const int grp = lane >> 4;

    // per-wave region: rows 0..15 = eT, rows 16..19 = wT; 136 hw rows (pad 8)
    __shared__ __align__(16) unsigned short sm[2][20][136];
    unsigned short (* __restrict__ eT)[136] = sm[w];
    unsigned short (* __restrict__ wT)[136] = sm[w] + 16;

    const float NL2E = -1.44269504088896340736f;

    const float nm16 = mu[15] * NL2E;
    const float nm14 = mu[13] * NL2E;
    const float nm12 = mu[11] * NL2E;
    const float nm10 = mu[9]  * NL2E;

    const float dl15 = mu[14] - mu[15];
    const float dl13 = mu[12] - mu[13];
    const float dl11 = mu[10] - mu[11];
    const float dl9  = mu[8]  - mu[9];
    const h2 hD15 = __builtin_amdgcn_cvt_pkrtz(dl15, dl15);
    const h2 hD13 = __builtin_amdgcn_cvt_pkrtz(dl13, dl13);
    const h2 hD11 = __builtin_amdgcn_cvt_pkrtz(dl11, dl11);
    const h2 hD9  = __builtin_amdgcn_cvt_pkrtz(dl9,  dl9);

    // cubic Taylor of exp(-x)
    const h2 C3 = {(__fp16)(-1.0f / 6.0f), (__fp16)(-1.0f / 6.0f)};
    const h2 C2 = {(__fp16)0.5f,  (__fp16)0.5f};
    const h2 C1 = {(__fp16)-1.0f, (__fp16)-1.0f};
    const h2 C0 = {(__fp16)1.0f,  (__fp16)1.0f};

    const float Rx = outc[(size_t)anchor * 3 + 0];
    const float Ry = outc[(size_t)anchor * 3 + 1];
    const float Rz = outc[(size_t)anchor * 3 + 2];

    f32x4 acc = {0.f, 0.f, 0.f, 0.f};

    const float* cb = coords + (size_t)b * NSRC * 3;
    const float* fb = f + (size_t)b * NSRC;

    // K-permuted write position for 2 sources/lane: chunk = lane>>4 (32 src),
    // t = lane&15 owns local sources (2t, 2t+1), both in one 4-quad.
    const int t = lane & 15;
    const int pos = (t < 8) ? (8 * (t >> 1) + 2 * (t & 1))
                            : (8 * ((t - 8) >> 1) + 4 + 2 * (t & 1));
    const int whw = 32 * (lane >> 4) + pos;
    const int rhw = 8 * grp;

    for (int i = 0; i < 8; ++i) {             // 8 iterations, 128 src each
        const int s0 = w * (NSRC / 2) + i * 128 + 2 * lane;  // lane: s0, s0+1
        const float2 c0 = *(const float2*)(cb + (size_t)s0 * 3);      // x0 y0
        const float2 c1 = *(const float2*)(cb + (size_t)s0 * 3 + 2);  // z0 x1
        const float2 c2 = *(const float2*)(cb + (size_t)s0 * 3 + 4);  // y1 z1
        const float2 f2 = *(const float2*)(fb + s0);

        const float dx0 = c0.x - Rx, dy0 = c0.y - Ry, dz0 = c1.x - Rz;
        const float dx1 = c1.y - Rx, dy1 = c2.x - Ry, dz1 = c2.y - Rz;

        const float sq0 = dx0 * dx0 + dy0 * dy0 + dz0 * dz0;
        const float sq1 = dx1 * dx1 + dy1 * dy1 + dz1 * dz1;
        const float ri0 = __builtin_amdgcn_rsqf(sq0);
        const float ri1 = __builtin_amdgcn_rsqf(sq1);
        const float d0 = sq0 * ri0, d1 = sq1 * ri1;
        const float t0 = f2.x * ri0, t1 = f2.y * ri1;

        const h2 dpk = __builtin_amdgcn_cvt_pkrtz(d0, d1);

        h2 ep[16];
        ep[15] = __builtin_amdgcn_cvt_pkrtz(
            __builtin_amdgcn_exp2f(d0 * nm16), __builtin_amdgcn_exp2f(d1 * nm16));
        ep[13] = __builtin_amdgcn_cvt_pkrtz(
            __builtin_amdgcn_exp2f(d0 * nm14), __builtin_amdgcn_exp2f(d1 * nm14));
        ep[11] = __builtin_amdgcn_cvt_pkrtz(
            __builtin_amdgcn_exp2f(d0 * nm12), __builtin_amdgcn_exp2f(d1 * nm12));
        ep[9]  = __builtin_amdgcn_cvt_pkrtz(
            __builtin_amdgcn_exp2f(d0 * nm10), __builtin_amdgcn_exp2f(d1 * nm10));

        ep[7] = ep[15] * ep[15];   // E8
        ep[6] = ep[13] * ep[13];   // E7
        ep[5] = ep[11] * ep[11];   // E6
        ep[4] = ep[9]  * ep[9];    // E5
        ep[3] = ep[7]  * ep[7];    // E4
        ep[2] = ep[5]  * ep[5];    // E3
        ep[1] = ep[3]  * ep[3];    // E2
        ep[0] = ep[1]  * ep[1];    // E1

#define ODD(K_ODD, K_EVEN, HD)                                            \
        {                                                                 \
            h2 x = dpk * (HD);                                            \
            h2 p = C0 + x * (C1 + x * (C2 + x * C3));                     \
            ep[K_ODD] = ep[K_EVEN] * p;                                   \
        }
        ODD(14, 15, hD15)   // E15 = E16 * corr
        ODD(12, 13, hD13)   // E13 = E14 * corr
        ODD(10, 11, hD11)   // E11 = E12 * corr
        ODD(8,  9,  hD9)    // E9  = E10 * corr
#undef ODD

        // LDS scatter: one b32 per row (2 sources)
#pragma unroll
        for (int k = 0; k < 16; ++k)
            *(unsigned*)&eT[k][whw] = __builtin_bit_cast(unsigned, ep[k]);
        *(unsigned*)&wT[0][whw] =
            __builtin_bit_cast(unsigned, __builtin_amdgcn_cvt_pkrtz(f2.x, f2.y));
        *(unsigned*)&wT[1][whw] =
            __builtin_bit_cast(unsigned, __builtin_amdgcn_cvt_pkrtz(t0 * dx0, t1 * dx1));
        *(unsigned*)&wT[2][whw] =
            __builtin_bit_cast(unsigned, __builtin_amdgcn_cvt_pkrtz(t0 * dy0, t1 * dy1));
        *(unsigned*)&wT[3][whw] =
            __builtin_bit_cast(unsigned, __builtin_amdgcn_cvt_pkrtz(t0 * dz0, t1 * dz1));

        // 4 MFMA chunks of 32 sources, b128 fragment reads
#pragma unroll
        for (int c = 0; c < 4; ++c) {
            const f16x8 av = *(const f16x8*)&eT[col][32 * c + rhw];
            const f16x8 bv = *(const f16x8*)&wT[col & 3][32 * c + rhw];
            acc = __builtin_amdgcn_mfma_f32_16x16x32_f16(av, bv, acc, 0, 0, 0);
        }
    }

    // cross-wave combine: wave1 parks acc in (its own, now-dead) LDS region
    if (w == 1) {
        float* red = (float*)&sm[1][0][0];
        *(f32x4*)&red[lane * 4] = acc;
    }
    __syncthreads();
    if (w == 0) {
        const float* red = (const float*)&sm[1][0][0];
        const f32x4 o2 = *(const f32x4*)&red[lane * 4];
        acc += o2;
        // D[row=4*grp+r][col]: col = component, row = k (m89-verified map)
        if (col < 4) {
            const float4 r4 = *(const float4*)&rn[4 * grp];
            const float an = (col == 0) ? an0[0] : an1[0];
            float4 o;
            o.x = acc[0] * r4.x * an;
            o.y = acc[1] * r4.y * an;
            o.z = acc[2] * r4.z * an;
            o.w = acc[3] * r4.w * an;
            *(float4*)&out[(size_t)anchor * 64 + col * 16 + 4 * grp] = o;
        }
    }
}

extern "C" void kernel_launch(void* const* d_in, const int* in_sizes, int n_in,
                              void* d_out, int out_size, void* d_ws, size_t ws_size,
                              hipStream_t stream) {
    const float* f      = (const float*)d_in[0];
    const float* coords = (const float*)d_in[1];
    const float* outc   = (const float*)d_in[2];
    const float* mu     = (const float*)d_in[3];
    const float* rn     = (const float*)d_in[4];
    const float* an0    = (const float*)d_in[5];
    const float* an1    = (const float*)d_in[6];
    float* out = (float*)d_out;

    const int anchors = BATCH * MOUT;              // 4096 blocks, 2 waves each
    svp_kernel<<<anchors, 128, 0, stream>>>(f, coords, outc, mu, rn, an0, an1, out);
}